// Round 12
// baseline (396.551 us; speedup 1.0000x reference)
//
#include <hip/hip_runtime.h>
#include <stdint.h>

#define NPOS 262144       // 512*512
#define EPS_LN 1e-5f
#define ZSTRIDE 272       // 128 f16 + 16B pad (breaks power-of-2 bank stride)

typedef _Float16 f16x8_t __attribute__((ext_vector_type(8)));
typedef float f32x4_t __attribute__((ext_vector_type(4)));

static __device__ __forceinline__ unsigned short f2h(float f) {
    union { _Float16 h; unsigned short u; } v;
    v.h = (_Float16)f;
    return v.u;
}
static __device__ __forceinline__ float h2f(unsigned short u) {
    union { unsigned short u; _Float16 h; } v;
    v.u = u;
    return (float)v.h;
}
static __device__ __forceinline__ float sigmoidf_(float x) {
    return 1.0f / (1.0f + expf(-x));
}

#define GLOAD_LDS16(gp, lp) __builtin_amdgcn_global_load_lds( \
    (const __attribute__((address_space(1))) void*)(gp), \
    (__attribute__((address_space(3))) void*)(lp), 16, 0, 0)

// ---------------------------------------------------------------------------
// k1c: fused LN(z) + a/b projections, weights in registers.
// 512 threads (8 waves), 128 positions/block, grid 2048.
// LN: 4 threads per position (k3b-validated pattern), coalesced z loads.
// ---------------------------------------------------------------------------
__global__ __launch_bounds__(512, 2)
void k1c(const float* __restrict__ z, const float* __restrict__ mask,
         const float* __restrict__ lng, const float* __restrict__ lnb,
         const float* __restrict__ w_ap, const float* __restrict__ b_ap,
         const float* __restrict__ w_ag, const float* __restrict__ b_ag,
         const float* __restrict__ w_bp, const float* __restrict__ b_bp,
         const float* __restrict__ w_bg, const float* __restrict__ b_bg,
         unsigned short* __restrict__ a_t, unsigned short* __restrict__ b_t,
         unsigned short* __restrict__ zn_out)
{
    __shared__ char sZn[128 * ZSTRIDE];  // [128 pos][128 ch] f16, padded rows
    const int t = threadIdx.x;
    const int lane = t & 63;
    const int w = t >> 6;                // wave 0..7
    const int g = lane >> 4;             // k-subgroup 0..3
    const int l15 = lane & 15;
    const int h = w * 16 + l15;          // this wave's output column
    const int p0 = blockIdx.x * 128;

    // ---- weight B-fragments into registers (L2-resident after block 0) ----
    f16x8_t wapf[4], wagf[4], wbpf[4], wbgf[4];
    #pragma unroll
    for (int kk = 0; kk < 4; ++kk) {
        #pragma unroll
        for (int j = 0; j < 8; ++j) {
            int k = kk * 32 + g * 8 + j;
            wapf[kk][j] = (_Float16)w_ap[(size_t)k * 128 + h];
            wagf[kk][j] = (_Float16)w_ag[(size_t)k * 128 + h];
            wbpf[kk][j] = (_Float16)w_bp[(size_t)k * 128 + h];
            wbgf[kk][j] = (_Float16)w_bg[(size_t)k * 128 + h];
        }
    }
    const float bap = b_ap[h], bag = b_ag[h];
    const float bbp = b_bp[h], bbg = b_bg[h];

    // ---- LN: 4 threads per position, values in registers ----
    {
        const int pos = t >> 2, q = t & 3;
        const float* zp = z + (size_t)(p0 + pos) * 128 + q * 32;
        float xs[32];
        #pragma unroll
        for (int e = 0; e < 8; ++e) {
            float4 v = *(const float4*)(zp + e * 4);
            xs[e * 4 + 0] = v.x; xs[e * 4 + 1] = v.y;
            xs[e * 4 + 2] = v.z; xs[e * 4 + 3] = v.w;
        }
        float s = 0.f, s2 = 0.f;
        #pragma unroll
        for (int e = 0; e < 32; ++e) { s += xs[e]; s2 += xs[e] * xs[e]; }
        s  += __shfl_xor(s, 1);  s  += __shfl_xor(s, 2);
        s2 += __shfl_xor(s2, 1); s2 += __shfl_xor(s2, 2);
        float mu = s * (1.0f / 128.0f);
        float var = s2 * (1.0f / 128.0f) - mu * mu;
        float rstd = rsqrtf(var + EPS_LN);
        #pragma unroll
        for (int e = 0; e < 8; ++e) {
            int cb = q * 32 + e * 4;
            float4 gg = *(const float4*)(lng + cb);
            float4 bb = *(const float4*)(lnb + cb);
            unsigned short o0 = f2h((xs[e * 4 + 0] - mu) * rstd * gg.x + bb.x);
            unsigned short o1 = f2h((xs[e * 4 + 1] - mu) * rstd * gg.y + bb.y);
            unsigned short o2 = f2h((xs[e * 4 + 2] - mu) * rstd * gg.z + bb.z);
            unsigned short o3 = f2h((xs[e * 4 + 3] - mu) * rstd * gg.w + bb.w);
            uint2 st;
            st.x = o0 | ((unsigned)o1 << 16);
            st.y = o2 | ((unsigned)o3 << 16);
            *(uint2*)(sZn + pos * ZSTRIDE + cb * 2) = st;
            *(uint2*)(zn_out + (size_t)(p0 + pos) * 128 + cb) = st;
        }
    }
    __syncthreads();

    // ---- MFMA row tiles: 16 positions at a time, all 4 projections ----
    f32x4_t zero = {0.f, 0.f, 0.f, 0.f};
    for (int rt = 0; rt < 8; ++rt) {
        f32x4_t accAP = zero, accAG = zero, accBP = zero, accBG = zero;
        #pragma unroll
        for (int kk = 0; kk < 4; ++kk) {
            f16x8_t ax = *(const f16x8_t*)(sZn + (rt * 16 + l15) * ZSTRIDE + kk * 64 + g * 16);
            accAP = __builtin_amdgcn_mfma_f32_16x16x32_f16(ax, wapf[kk], accAP, 0, 0, 0);
            accAG = __builtin_amdgcn_mfma_f32_16x16x32_f16(ax, wagf[kk], accAG, 0, 0, 0);
            accBP = __builtin_amdgcn_mfma_f32_16x16x32_f16(ax, wbpf[kk], accBP, 0, 0, 0);
            accBG = __builtin_amdgcn_mfma_f32_16x16x32_f16(ax, wbgf[kk], accBG, 0, 0, 0);
        }
        int pb = p0 + rt * 16 + g * 4;
        unsigned short pka[4], pkb[4];
        #pragma unroll
        for (int r = 0; r < 4; ++r) {
            float m = mask[pb + r];
            pka[r] = f2h(m * sigmoidf_(accAG[r] + bag) * (accAP[r] + bap));
            pkb[r] = f2h(m * sigmoidf_(accBG[r] + bbg) * (accBP[r] + bbp));
        }
        uint2 sta, stb;
        sta.x = pka[0] | ((unsigned)pka[1] << 16);
        sta.y = pka[2] | ((unsigned)pka[3] << 16);
        stb.x = pkb[0] | ((unsigned)pkb[1] << 16);
        stb.y = pkb[2] | ((unsigned)pkb[3] << 16);
        *(uint2*)(a_t + (size_t)h * NPOS + pb) = sta;
        *(uint2*)(b_t + (size_t)h * NPOS + pb) = stb;
    }
}

// ---------------------------------------------------------------------------
// k2 (VALIDATED R7): per-h triangle GEMM
//   x_t[h][i][k] = sum_j a_t[h][i][j] * b_t[h][k][j]
// ---------------------------------------------------------------------------
__global__ __launch_bounds__(256, 2)
void k2_tri(const unsigned short* __restrict__ a_t,
            const unsigned short* __restrict__ b_t,
            unsigned short* __restrict__ x_t) {
    __shared__ char sA[16384];   // [128][64] f16 linear
    __shared__ char sB[16384];
    const int t = threadIdx.x;
    const int lane = t & 63;
    const int w = t >> 6;
    const int wr = w >> 1, wc = w & 1;
    const int h = blockIdx.y;
    const int i0 = (blockIdx.x >> 2) * 128;
    const int k0 = (blockIdx.x & 3) * 128;
    const unsigned short* Abase = a_t + (size_t)h * NPOS;
    const unsigned short* Bbase = b_t + (size_t)h * NPOS;

    f32x4_t zero = {0.f, 0.f, 0.f, 0.f};
    f32x4_t acc[4][4];
    #pragma unroll
    for (int m = 0; m < 4; ++m)
        #pragma unroll
        for (int n = 0; n < 4; ++n) acc[m][n] = zero;

    for (int kt = 0; kt < 8; ++kt) {
        #pragma unroll
        for (int pass = 0; pass < 4; ++pass) {
            int ci = pass * 256 + t;
            int row = ci >> 3, ch = ci & 7;
            const unsigned short* gA = Abase + (size_t)(i0 + row) * 512 + kt * 64 + ch * 8;
            const unsigned short* gB = Bbase + (size_t)(k0 + row) * 512 + kt * 64 + ch * 8;
            GLOAD_LDS16(gA, sA + w * 1024 + pass * 4096);
            GLOAD_LDS16(gB, sB + w * 1024 + pass * 4096);
        }
        __syncthreads();
        #pragma unroll
        for (int ks = 0; ks < 2; ++ks) {
            f16x8_t af[4], bf[4];
            #pragma unroll
            for (int m = 0; m < 4; ++m) {
                int ar = wr * 64 + m * 16 + (lane & 15);
                af[m] = *(const f16x8_t*)(sA + ar * 128 + ks * 64 + (lane >> 4) * 16);
            }
            #pragma unroll
            for (int n = 0; n < 4; ++n) {
                int br = wc * 64 + n * 16 + (lane & 15);
                bf[n] = *(const f16x8_t*)(sB + br * 128 + ks * 64 + (lane >> 4) * 16);
            }
            #pragma unroll
            for (int m = 0; m < 4; ++m)
                #pragma unroll
                for (int n = 0; n < 4; ++n)
                    acc[m][n] = __builtin_amdgcn_mfma_f32_16x16x32_f16(af[m], bf[n], acc[m][n], 0, 0, 0);
        }
        __syncthreads();
    }
    #pragma unroll
    for (int m = 0; m < 4; ++m) {
        int i = i0 + wr * 64 + m * 16 + (lane >> 4) * 4;
        #pragma unroll
        for (int n = 0; n < 4; ++n) {
            int k = k0 + wc * 64 + n * 16 + (lane & 15);
            #pragma unroll
            for (int r = 0; r < 4; ++r) {
                x_t[(size_t)h * NPOS + (size_t)(i + r) * 512 + k] = f2h(acc[m][n][r]);
            }
        }
    }
}

// ---------------------------------------------------------------------------
// k3b: out[p][c] = (LN_h(x[:,p])@w_z+b_z)*sigmoid(zn[p]@w_g+b_g)
// x-stage: lane = h-pair, wave = 16-p segment; 4-byte packed LDS stores
// (256 B contiguous per wave-store => conflict-free).
// ---------------------------------------------------------------------------
__global__ __launch_bounds__(512, 2)
void k3b(const unsigned short* __restrict__ x_t,
         const unsigned short* __restrict__ zn,
         const float* __restrict__ lngo, const float* __restrict__ lnbo,
         const float* __restrict__ w_z, const float* __restrict__ b_z,
         const float* __restrict__ w_g, const float* __restrict__ b_g,
         float* __restrict__ out)
{
    __shared__ char sX[128 * ZSTRIDE];   // [128 pos][128 h] f16, padded rows
    const int t = threadIdx.x, lane = t & 63, w = t >> 6;
    const int g = lane >> 4;             // k-subgroup 0..3
    const int c = w * 16 + (lane & 15);  // this wave's output column
    const int p0 = blockIdx.x * 128;

    // ---- weight fragments into registers (issue early; L2-resident) ----
    f16x8_t wzf[4], wgf[4];
    #pragma unroll
    for (int kk = 0; kk < 4; ++kk) {
        #pragma unroll
        for (int j = 0; j < 8; ++j) {
            int k = kk * 32 + g * 8 + j;
            wzf[kk][j] = (_Float16)w_z[(size_t)k * 128 + c];
            wgf[kk][j] = (_Float16)w_g[(size_t)k * 128 + c];
        }
    }
    const float bzv = b_z[c], bgv = b_g[c];

    // ---- stage x transposed: lane = h-pair (h=2*lane,2*lane+1), wave = p seg
    {
        const int hp = lane;
        const int ps = w * 16;
        const unsigned short* x0 = x_t + (size_t)(2 * hp) * NPOS + p0 + ps;
        const unsigned short* x1 = x_t + (size_t)(2 * hp + 1) * NPOS + p0 + ps;
        uint4 a0 = *(const uint4*)(x0);
        uint4 a1 = *(const uint4*)(x0 + 8);
        uint4 b0 = *(const uint4*)(x1);
        uint4 b1 = *(const uint4*)(x1 + 8);
        unsigned aw[8] = {a0.x, a0.y, a0.z, a0.w, a1.x, a1.y, a1.z, a1.w};
        unsigned bw[8] = {b0.x, b0.y, b0.z, b0.w, b1.x, b1.y, b1.z, b1.w};
        #pragma unroll
        for (int e = 0; e < 8; ++e) {
            int p = ps + 2 * e;
            *(unsigned*)(sX + p * ZSTRIDE + hp * 4) =
                (aw[e] & 0xffffu) | ((bw[e] & 0xffffu) << 16);
            *(unsigned*)(sX + (p + 1) * ZSTRIDE + hp * 4) =
                (aw[e] >> 16) | ((bw[e] >> 16) << 16);
        }
    }
    __syncthreads();
    // ---- LN over h, in place (4 threads per position) ----
    {
        int pos = t >> 2, q = t & 3;
        float xs[32];
        #pragma unroll
        for (int e = 0; e < 8; ++e) {
            uint2 vv = *(const uint2*)(sX + pos * ZSTRIDE + (q * 32 + e * 4) * 2);
            xs[e * 4 + 0] = h2f((unsigned short)(vv.x & 0xffffu));
            xs[e * 4 + 1] = h2f((unsigned short)(vv.x >> 16));
            xs[e * 4 + 2] = h2f((unsigned short)(vv.y & 0xffffu));
            xs[e * 4 + 3] = h2f((unsigned short)(vv.y >> 16));
        }
        float s = 0.f, s2 = 0.f;
        #pragma unroll
        for (int e = 0; e < 32; ++e) { s += xs[e]; s2 += xs[e] * xs[e]; }
        s  += __shfl_xor(s, 1);  s  += __shfl_xor(s, 2);
        s2 += __shfl_xor(s2, 1); s2 += __shfl_xor(s2, 2);
        float mu = s * (1.0f / 128.0f);
        float var = s2 * (1.0f / 128.0f) - mu * mu;
        float rstd = rsqrtf(var + EPS_LN);
        #pragma unroll
        for (int e = 0; e < 8; ++e) {
            int hb = q * 32 + e * 4;
            float4 gg = *(const float4*)(lngo + hb);
            float4 bb = *(const float4*)(lnbo + hb);
            unsigned short o0 = f2h((xs[e * 4 + 0] - mu) * rstd * gg.x + bb.x);
            unsigned short o1 = f2h((xs[e * 4 + 1] - mu) * rstd * gg.y + bb.y);
            unsigned short o2 = f2h((xs[e * 4 + 2] - mu) * rstd * gg.z + bb.z);
            unsigned short o3 = f2h((xs[e * 4 + 3] - mu) * rstd * gg.w + bb.w);
            uint2 st;
            st.x = o0 | ((unsigned)o1 << 16);
            st.y = o2 | ((unsigned)o3 << 16);
            *(uint2*)(sX + pos * ZSTRIDE + hb * 2) = st;
        }
    }
    __syncthreads();
    // ---- MFMA row tiles: D[pos][c] for 16 pos at a time ----
    f32x4_t zero = {0.f, 0.f, 0.f, 0.f};
    for (int rt = 0; rt < 8; ++rt) {
        f32x4_t accZ = zero, accG = zero;
        #pragma unroll
        for (int kk = 0; kk < 4; ++kk) {
            int row = rt * 16 + (lane & 15);
            f16x8_t ax = *(const f16x8_t*)(sX + row * ZSTRIDE + kk * 64 + g * 16);
            f16x8_t az = *(const f16x8_t*)(zn + (size_t)(p0 + row) * 128 + kk * 32 + g * 8);
            accZ = __builtin_amdgcn_mfma_f32_16x16x32_f16(ax, wzf[kk], accZ, 0, 0, 0);
            accG = __builtin_amdgcn_mfma_f32_16x16x32_f16(az, wgf[kk], accG, 0, 0, 0);
        }
        int prow = p0 + rt * 16 + g * 4;
        #pragma unroll
        for (int r = 0; r < 4; ++r) {
            out[(size_t)(prow + r) * 128 + c] = (accZ[r] + bzv) * sigmoidf_(accG[r] + bgv);
        }
    }
}

extern "C" void kernel_launch(void* const* d_in, const int* in_sizes, int n_in,
                              void* d_out, int out_size, void* d_ws, size_t ws_size,
                              hipStream_t stream) {
    const float* z        = (const float*)d_in[0];
    const float* mask     = (const float*)d_in[1];
    const float* ln_in_g  = (const float*)d_in[2];
    const float* ln_in_b  = (const float*)d_in[3];
    const float* w_ap     = (const float*)d_in[4];
    const float* b_ap     = (const float*)d_in[5];
    const float* w_ag     = (const float*)d_in[6];
    const float* b_ag     = (const float*)d_in[7];
    const float* w_bp     = (const float*)d_in[8];
    const float* b_bp     = (const float*)d_in[9];
    const float* w_bg     = (const float*)d_in[10];
    const float* b_bg     = (const float*)d_in[11];
    const float* w_g      = (const float*)d_in[12];
    const float* b_g      = (const float*)d_in[13];
    const float* ln_out_g = (const float*)d_in[14];
    const float* ln_out_b = (const float*)d_in[15];
    const float* w_z      = (const float*)d_in[16];
    const float* b_z      = (const float*)d_in[17];
    float* out = (float*)d_out;

    char* ws = (char*)d_ws;
    const size_t MB64 = (size_t)NPOS * 128 * 2;   // 64 MB per f16 plane-set
    unsigned short* a_t  = (unsigned short*)(ws);
    unsigned short* b_t  = (unsigned short*)(ws + MB64);
    unsigned short* x_t  = (unsigned short*)(ws + 2 * MB64);
    unsigned short* zn_p = (unsigned short*)(ws + 3 * MB64);  // 256 MB total

    k1c<<<2048, 512, 0, stream>>>(z, mask, ln_in_g, ln_in_b,
                                  w_ap, b_ap, w_ag, b_ag,
                                  w_bp, b_bp, w_bg, b_bg,
                                  a_t, b_t, zn_p);
    k2_tri<<<dim3(16, 128), 256, 0, stream>>>(a_t, b_t, x_t);
    k3b<<<2048, 512, 0, stream>>>(x_t, zn_p, ln_out_g, ln_out_b,
                                  w_z, b_z, w_g, b_g, out);
}

// Round 13
// 368.001 us; speedup vs baseline: 1.0776x; 1.0776x over previous
//
#include <hip/hip_runtime.h>
#include <stdint.h>

#define NPOS 262144       // 512*512
#define EPS_LN 1e-5f
#define ZSTRIDE 272       // 128 f16 + 16B pad (breaks power-of-2 bank stride)

typedef _Float16 f16x8_t __attribute__((ext_vector_type(8)));
typedef float f32x4_t __attribute__((ext_vector_type(4)));

static __device__ __forceinline__ unsigned short f2h(float f) {
    union { _Float16 h; unsigned short u; } v;
    v.h = (_Float16)f;
    return v.u;
}
static __device__ __forceinline__ float h2f(unsigned short u) {
    union { unsigned short u; _Float16 h; } v;
    v.u = u;
    return (float)v.h;
}
static __device__ __forceinline__ float sigmoidf_(float x) {
    return 1.0f / (1.0f + expf(-x));
}

#define GLOAD_LDS16(gp, lp) __builtin_amdgcn_global_load_lds( \
    (const __attribute__((address_space(1))) void*)(gp), \
    (__attribute__((address_space(3))) void*)(lp), 16, 0, 0)

// ---------------------------------------------------------------------------
// k_prep6: transpose+cast 6 weight matrices f32 [k][h] -> f16 h-major [h][k].
// plane order: ap, ag, bp, bg, z, g   (each 16384 f16)
// ---------------------------------------------------------------------------
__global__ __launch_bounds__(256)
void k_prep6(const float* w0, const float* w1, const float* w2,
             const float* w3, const float* w4, const float* w5,
             unsigned short* wt) {
    const float* srcs[6] = {w0, w1, w2, w3, w4, w5};
    const float* src = srcs[blockIdx.x];
    unsigned short* dst = wt + blockIdx.x * 16384;
    for (int rep = 0; rep < 64; ++rep) {
        int idx = rep * 256 + threadIdx.x;   // 0..16383
        int h = idx >> 7, k = idx & 127;
        dst[idx] = f2h(src[k * 128 + h]);    // dst[h*128+k] = src[k][h]
    }
}

// ---------------------------------------------------------------------------
// k1c: fused LN(z) + a/b projections, weights (pre-transposed f16) in regs.
// 512 threads (8 waves), 128 positions/block, grid 2048.
// LN: R11-validated per-row form (wave w -> rows w*16..w*16+15).
// ---------------------------------------------------------------------------
__global__ __launch_bounds__(512, 2)
void k1c(const float* __restrict__ z, const float* __restrict__ mask,
         const float* __restrict__ lng, const float* __restrict__ lnb,
         const unsigned short* __restrict__ wt,
         const float* __restrict__ b_ap, const float* __restrict__ b_ag,
         const float* __restrict__ b_bp, const float* __restrict__ b_bg,
         unsigned short* __restrict__ a_t, unsigned short* __restrict__ b_t,
         unsigned short* __restrict__ zn_out)
{
    __shared__ char sZn[128 * ZSTRIDE];  // [128 pos][128 ch] f16, padded rows
    const int t = threadIdx.x;
    const int lane = t & 63;
    const int w = t >> 6;                // wave 0..7
    const int g = lane >> 4;             // k-subgroup 0..3
    const int l15 = lane & 15;
    const int h = w * 16 + l15;          // this wave's output column
    const int p0 = blockIdx.x * 128;

    // ---- weight B-fragments: 16 vector loads (f16 h-major planes) ----
    f16x8_t wapf[4], wagf[4], wbpf[4], wbgf[4];
    #pragma unroll
    for (int kk = 0; kk < 4; ++kk) {
        int off = h * 128 + kk * 32 + g * 8;
        wapf[kk] = *(const f16x8_t*)(wt + 0 * 16384 + off);
        wagf[kk] = *(const f16x8_t*)(wt + 1 * 16384 + off);
        wbpf[kk] = *(const f16x8_t*)(wt + 2 * 16384 + off);
        wbgf[kk] = *(const f16x8_t*)(wt + 3 * 16384 + off);
    }
    const float bap = b_ap[h], bag = b_ag[h];
    const float bbp = b_bp[h], bbg = b_bg[h];

    // ---- LN staging (R11-validated): wave w rows w*16..w*16+15 ----
    {
        const float g0 = lng[2 * lane], g1 = lng[2 * lane + 1];
        const float e0 = lnb[2 * lane], e1 = lnb[2 * lane + 1];
        for (int i = 0; i < 16; ++i) {
            int r = w * 16 + i;
            const float* zp = z + (size_t)(p0 + r) * 128 + 2 * lane;
            float v0 = zp[0], v1 = zp[1];
            float s = v0 + v1, s2 = v0 * v0 + v1 * v1;
            #pragma unroll
            for (int off = 1; off < 64; off <<= 1) {
                s  += __shfl_xor(s, off);
                s2 += __shfl_xor(s2, off);
            }
            float mu = s * (1.0f / 128.0f);
            float var = s2 * (1.0f / 128.0f) - mu * mu;
            float rstd = rsqrtf(var + EPS_LN);
            unsigned short h0 = f2h((v0 - mu) * rstd * g0 + e0);
            unsigned short h1 = f2h((v1 - mu) * rstd * g1 + e1);
            unsigned pk = h0 | ((unsigned)h1 << 16);
            *(unsigned*)(sZn + r * ZSTRIDE + lane * 4) = pk;
            *(unsigned*)(zn_out + (size_t)(p0 + r) * 128 + 2 * lane) = pk;
        }
    }
    __syncthreads();

    // ---- MFMA row tiles: 16 positions at a time, all 4 projections ----
    f32x4_t zero = {0.f, 0.f, 0.f, 0.f};
    for (int rt = 0; rt < 8; ++rt) {
        f32x4_t accAP = zero, accAG = zero, accBP = zero, accBG = zero;
        #pragma unroll
        for (int kk = 0; kk < 4; ++kk) {
            f16x8_t ax = *(const f16x8_t*)(sZn + (rt * 16 + l15) * ZSTRIDE + kk * 64 + g * 16);
            accAP = __builtin_amdgcn_mfma_f32_16x16x32_f16(ax, wapf[kk], accAP, 0, 0, 0);
            accAG = __builtin_amdgcn_mfma_f32_16x16x32_f16(ax, wagf[kk], accAG, 0, 0, 0);
            accBP = __builtin_amdgcn_mfma_f32_16x16x32_f16(ax, wbpf[kk], accBP, 0, 0, 0);
            accBG = __builtin_amdgcn_mfma_f32_16x16x32_f16(ax, wbgf[kk], accBG, 0, 0, 0);
        }
        int pb = p0 + rt * 16 + g * 4;
        unsigned short pka[4], pkb[4];
        #pragma unroll
        for (int r = 0; r < 4; ++r) {
            float m = mask[pb + r];
            pka[r] = f2h(m * sigmoidf_(accAG[r] + bag) * (accAP[r] + bap));
            pkb[r] = f2h(m * sigmoidf_(accBG[r] + bbg) * (accBP[r] + bbp));
        }
        uint2 sta, stb;
        sta.x = pka[0] | ((unsigned)pka[1] << 16);
        sta.y = pka[2] | ((unsigned)pka[3] << 16);
        stb.x = pkb[0] | ((unsigned)pkb[1] << 16);
        stb.y = pkb[2] | ((unsigned)pkb[3] << 16);
        *(uint2*)(a_t + (size_t)h * NPOS + pb) = sta;
        *(uint2*)(b_t + (size_t)h * NPOS + pb) = stb;
    }
}

// ---------------------------------------------------------------------------
// k2 (VALIDATED R7): per-h triangle GEMM
//   x_t[h][i][k] = sum_j a_t[h][i][j] * b_t[h][k][j]
// ---------------------------------------------------------------------------
__global__ __launch_bounds__(256, 2)
void k2_tri(const unsigned short* __restrict__ a_t,
            const unsigned short* __restrict__ b_t,
            unsigned short* __restrict__ x_t) {
    __shared__ char sA[16384];   // [128][64] f16 linear
    __shared__ char sB[16384];
    const int t = threadIdx.x;
    const int lane = t & 63;
    const int w = t >> 6;
    const int wr = w >> 1, wc = w & 1;
    const int h = blockIdx.y;
    const int i0 = (blockIdx.x >> 2) * 128;
    const int k0 = (blockIdx.x & 3) * 128;
    const unsigned short* Abase = a_t + (size_t)h * NPOS;
    const unsigned short* Bbase = b_t + (size_t)h * NPOS;

    f32x4_t zero = {0.f, 0.f, 0.f, 0.f};
    f32x4_t acc[4][4];
    #pragma unroll
    for (int m = 0; m < 4; ++m)
        #pragma unroll
        for (int n = 0; n < 4; ++n) acc[m][n] = zero;

    for (int kt = 0; kt < 8; ++kt) {
        #pragma unroll
        for (int pass = 0; pass < 4; ++pass) {
            int ci = pass * 256 + t;
            int row = ci >> 3, ch = ci & 7;
            const unsigned short* gA = Abase + (size_t)(i0 + row) * 512 + kt * 64 + ch * 8;
            const unsigned short* gB = Bbase + (size_t)(k0 + row) * 512 + kt * 64 + ch * 8;
            GLOAD_LDS16(gA, sA + w * 1024 + pass * 4096);
            GLOAD_LDS16(gB, sB + w * 1024 + pass * 4096);
        }
        __syncthreads();
        #pragma unroll
        for (int ks = 0; ks < 2; ++ks) {
            f16x8_t af[4], bf[4];
            #pragma unroll
            for (int m = 0; m < 4; ++m) {
                int ar = wr * 64 + m * 16 + (lane & 15);
                af[m] = *(const f16x8_t*)(sA + ar * 128 + ks * 64 + (lane >> 4) * 16);
            }
            #pragma unroll
            for (int n = 0; n < 4; ++n) {
                int br = wc * 64 + n * 16 + (lane & 15);
                bf[n] = *(const f16x8_t*)(sB + br * 128 + ks * 64 + (lane >> 4) * 16);
            }
            #pragma unroll
            for (int m = 0; m < 4; ++m)
                #pragma unroll
                for (int n = 0; n < 4; ++n)
                    acc[m][n] = __builtin_amdgcn_mfma_f32_16x16x32_f16(af[m], bf[n], acc[m][n], 0, 0, 0);
        }
        __syncthreads();
    }
    #pragma unroll
    for (int m = 0; m < 4; ++m) {
        int i = i0 + wr * 64 + m * 16 + (lane >> 4) * 4;
        #pragma unroll
        for (int n = 0; n < 4; ++n) {
            int k = k0 + wc * 64 + n * 16 + (lane & 15);
            #pragma unroll
            for (int r = 0; r < 4; ++r) {
                x_t[(size_t)h * NPOS + (size_t)(i + r) * 512 + k] = f2h(acc[m][n][r]);
            }
        }
    }
}

// ---------------------------------------------------------------------------
// k3b: out[p][c] = (LN_h(x[:,p])@w_z+b_z)*sigmoid(zn[p]@w_g+b_g)
// weights from pre-transposed f16 planes; packed 4B LDS transpose stores.
// ---------------------------------------------------------------------------
__global__ __launch_bounds__(512, 2)
void k3b(const unsigned short* __restrict__ x_t,
         const unsigned short* __restrict__ zn,
         const float* __restrict__ lngo, const float* __restrict__ lnbo,
         const unsigned short* __restrict__ wt,
         const float* __restrict__ b_z, const float* __restrict__ b_g,
         float* __restrict__ out)
{
    __shared__ char sX[128 * ZSTRIDE];   // [128 pos][128 h] f16, padded rows
    const int t = threadIdx.x, lane = t & 63, w = t >> 6;
    const int g = lane >> 4;             // k-subgroup 0..3
    const int c = w * 16 + (lane & 15);  // this wave's output column
    const int p0 = blockIdx.x * 128;

    // ---- weight fragments: 8 vector loads ----
    f16x8_t wzf[4], wgf[4];
    #pragma unroll
    for (int kk = 0; kk < 4; ++kk) {
        int off = c * 128 + kk * 32 + g * 8;
        wzf[kk] = *(const f16x8_t*)(wt + 4 * 16384 + off);
        wgf[kk] = *(const f16x8_t*)(wt + 5 * 16384 + off);
    }
    const float bzv = b_z[c], bgv = b_g[c];

    // ---- stage x transposed: lane = h-pair, wave = 16-p segment ----
    {
        const int hp = lane;
        const int ps = w * 16;
        const unsigned short* x0 = x_t + (size_t)(2 * hp) * NPOS + p0 + ps;
        const unsigned short* x1 = x_t + (size_t)(2 * hp + 1) * NPOS + p0 + ps;
        uint4 a0 = *(const uint4*)(x0);
        uint4 a1 = *(const uint4*)(x0 + 8);
        uint4 b0 = *(const uint4*)(x1);
        uint4 b1 = *(const uint4*)(x1 + 8);
        unsigned aw[8] = {a0.x, a0.y, a0.z, a0.w, a1.x, a1.y, a1.z, a1.w};
        unsigned bw[8] = {b0.x, b0.y, b0.z, b0.w, b1.x, b1.y, b1.z, b1.w};
        #pragma unroll
        for (int e = 0; e < 8; ++e) {
            int p = ps + 2 * e;
            *(unsigned*)(sX + p * ZSTRIDE + hp * 4) =
                (aw[e] & 0xffffu) | ((bw[e] & 0xffffu) << 16);
            *(unsigned*)(sX + (p + 1) * ZSTRIDE + hp * 4) =
                (aw[e] >> 16) | ((bw[e] >> 16) << 16);
        }
    }
    __syncthreads();
    // ---- LN over h, in place (4 threads per position) ----
    {
        int pos = t >> 2, q = t & 3;
        float xs[32];
        #pragma unroll
        for (int e = 0; e < 8; ++e) {
            uint2 vv = *(const uint2*)(sX + pos * ZSTRIDE + (q * 32 + e * 4) * 2);
            xs[e * 4 + 0] = h2f((unsigned short)(vv.x & 0xffffu));
            xs[e * 4 + 1] = h2f((unsigned short)(vv.x >> 16));
            xs[e * 4 + 2] = h2f((unsigned short)(vv.y & 0xffffu));
            xs[e * 4 + 3] = h2f((unsigned short)(vv.y >> 16));
        }
        float s = 0.f, s2 = 0.f;
        #pragma unroll
        for (int e = 0; e < 32; ++e) { s += xs[e]; s2 += xs[e] * xs[e]; }
        s  += __shfl_xor(s, 1);  s  += __shfl_xor(s, 2);
        s2 += __shfl_xor(s2, 1); s2 += __shfl_xor(s2, 2);
        float mu = s * (1.0f / 128.0f);
        float var = s2 * (1.0f / 128.0f) - mu * mu;
        float rstd = rsqrtf(var + EPS_LN);
        #pragma unroll
        for (int e = 0; e < 8; ++e) {
            int hb = q * 32 + e * 4;
            float4 gg = *(const float4*)(lngo + hb);
            float4 bb = *(const float4*)(lnbo + hb);
            unsigned short o0 = f2h((xs[e * 4 + 0] - mu) * rstd * gg.x + bb.x);
            unsigned short o1 = f2h((xs[e * 4 + 1] - mu) * rstd * gg.y + bb.y);
            unsigned short o2 = f2h((xs[e * 4 + 2] - mu) * rstd * gg.z + bb.z);
            unsigned short o3 = f2h((xs[e * 4 + 3] - mu) * rstd * gg.w + bb.w);
            uint2 st;
            st.x = o0 | ((unsigned)o1 << 16);
            st.y = o2 | ((unsigned)o3 << 16);
            *(uint2*)(sX + pos * ZSTRIDE + hb * 2) = st;
        }
    }
    __syncthreads();
    // ---- MFMA row tiles: D[pos][c] for 16 pos at a time ----
    f32x4_t zero = {0.f, 0.f, 0.f, 0.f};
    for (int rt = 0; rt < 8; ++rt) {
        f32x4_t accZ = zero, accG = zero;
        #pragma unroll
        for (int kk = 0; kk < 4; ++kk) {
            int row = rt * 16 + (lane & 15);
            f16x8_t ax = *(const f16x8_t*)(sX + row * ZSTRIDE + kk * 64 + g * 16);
            f16x8_t az = *(const f16x8_t*)(zn + (size_t)(p0 + row) * 128 + kk * 32 + g * 8);
            accZ = __builtin_amdgcn_mfma_f32_16x16x32_f16(ax, wzf[kk], accZ, 0, 0, 0);
            accG = __builtin_amdgcn_mfma_f32_16x16x32_f16(az, wgf[kk], accG, 0, 0, 0);
        }
        int prow = p0 + rt * 16 + g * 4;
        #pragma unroll
        for (int r = 0; r < 4; ++r) {
            out[(size_t)(prow + r) * 128 + c] = (accZ[r] + bzv) * sigmoidf_(accG[r] + bgv);
        }
    }
}

extern "C" void kernel_launch(void* const* d_in, const int* in_sizes, int n_in,
                              void* d_out, int out_size, void* d_ws, size_t ws_size,
                              hipStream_t stream) {
    const float* z        = (const float*)d_in[0];
    const float* mask     = (const float*)d_in[1];
    const float* ln_in_g  = (const float*)d_in[2];
    const float* ln_in_b  = (const float*)d_in[3];
    const float* w_ap     = (const float*)d_in[4];
    const float* b_ap     = (const float*)d_in[5];
    const float* w_ag     = (const float*)d_in[6];
    const float* b_ag     = (const float*)d_in[7];
    const float* w_bp     = (const float*)d_in[8];
    const float* b_bp     = (const float*)d_in[9];
    const float* w_bg     = (const float*)d_in[10];
    const float* b_bg     = (const float*)d_in[11];
    const float* w_g      = (const float*)d_in[12];
    const float* b_g      = (const float*)d_in[13];
    const float* ln_out_g = (const float*)d_in[14];
    const float* ln_out_b = (const float*)d_in[15];
    const float* w_z      = (const float*)d_in[16];
    const float* b_z      = (const float*)d_in[17];
    float* out = (float*)d_out;

    char* ws = (char*)d_ws;
    const size_t MB64 = (size_t)NPOS * 128 * 2;   // 64 MB per f16 plane-set
    unsigned short* wt   = (unsigned short*)(ws);              // 192 KB
    unsigned short* a_t  = (unsigned short*)(ws + (1 << 20));
    unsigned short* b_t  = (unsigned short*)(ws + (1 << 20) + MB64);
    unsigned short* x_t  = (unsigned short*)(ws + (1 << 20) + 2 * MB64);
    unsigned short* zn_p = (unsigned short*)(ws + (1 << 20) + 3 * MB64); // 257 MB

    k_prep6<<<6, 256, 0, stream>>>(w_ap, w_ag, w_bp, w_bg, w_z, w_g, wt);
    k1c<<<2048, 512, 0, stream>>>(z, mask, ln_in_g, ln_in_b, wt,
                                  b_ap, b_ag, b_bp, b_bg,
                                  a_t, b_t, zn_p);
    k2_tri<<<dim3(16, 128), 256, 0, stream>>>(a_t, b_t, x_t);
    k3b<<<2048, 512, 0, stream>>>(x_t, zn_p, ln_out_g, ln_out_b, wt,
                                  b_z, b_g, out);
}